// Round 2
// baseline (143.062 us; speedup 1.0000x reference)
//
#include <hip/hip_runtime.h>

// NCC loss, win=9, (1,1,160,192,224) fp32 -> scalar. Fully fused, round 11.
// R10 post-mortem: dur 70.7->63us, VALU 37%, occ only 35%. With VGPR=60 and
// LDS=22KB the CU can hold ~7 blocks (LDS-limited) / 8 waves/SIMD (reg-
// limited) -- but the grid only supplied 1008 blocks = 3.94/CU. Occupancy is
// LAUNCH-limited. R11 = R10 with ONE change: DCH 28->19 -> grid.z=9 ->
// 7x24x9 = 1512 blocks = 5.9/CU (under the 7-block LDS cap, all co-resident)
// -> ~24 waves/CU for latency hiding. ITERS=27=3x9 keeps ring phase-static.
// Cost: +12.5% slice-iterations (D-halo 27/19 vs 36/28), ~+11% fetch.
// Structure unchanged from R10:
//   phases {H(i)} barA {W(i+1) || F(i)} barB; single SW, SH double-buffered;
//   barriers LDS-only (vmcnt unconstrained) so pf global loads span them.

#define DD 160
#define HH 192
#define WW 224
#define W4 56                 // WW/4
#define SLICE (HH * WW)
#define S4 (SLICE / 4)
#define NVOX (DD * SLICE)
#define TW 32
#define TH 8
#define DCH 19                // grid.z = 9 -> 1512 blocks (~5.9/CU, cap 7)
#define ITERS (DCH + 8)       // 27 = 3 * 9 (phase-static ring)
#define NTHR 256
#define SW_RS 36              // b128-aligned rows; 0-conflict pattern (R5/R7)
#define SW_CS (16 * SW_RS)    // 576 floats: 16 rows = TH + 8
#define SH_SZ (TH * TW * 5)   // 1280 floats
#define EPS 1e-5f
#define INV_WSUM (1.0f / 729.0f)

// Barrier that orders LDS only: s_waitcnt imm 0xC07F = lgkmcnt(0), vmcnt(63),
// expcnt(7) -> in-flight GLOBAL loads stay in flight across the barrier.
__device__ __forceinline__ void bar_lds_only() {
    __asm__ volatile("" ::: "memory");
    __builtin_amdgcn_s_waitcnt(0xC07F);
    __builtin_amdgcn_s_barrier();
    __asm__ volatile("" ::: "memory");
}

__global__ __launch_bounds__(NTHR, 4) void ncc_fused(const float* __restrict__ I,
                                                     const float* __restrict__ J,
                                                     float* __restrict__ out) {
    __shared__ float SW[5 * SW_CS];            // 11.52 KB, single buffer
    __shared__ float SH0[SH_SZ], SH1[SH_SZ];   // 5.12 KB each, double buffer
    __shared__ float wred[NTHR / 64];

    const int tid = threadIdx.x;
    const int tx = tid & 31, ty = tid >> 5;    // F mapping: 32 x 8
    const int wlo = blockIdx.x * TW;
    const int hlo = blockIdx.y * TH;
    const int dlo = blockIdx.z * DCH;

    // W-group (tid >= 128): 16 rows x 8 f4-col groups
    const int wid = tid - 128;
    const int wr = wid >> 3, wc = wid & 7;
    const int gh = hlo - 4 + wr;
    const bool hok = (gh >= 0) && (gh < HH);
    const int gf0 = (wlo >> 2) - 1 + wc;

    // H-group (tid < 160): 5 channels x 32 cols, 8 out-rows each (16 reads)
    const int hcol = tid & 31, hch = tid >> 5;

    const float4* Iv = (const float4*)I;
    const float4* Jv = (const float4*)J;

    // prefetch registers: one slice-row of raw I/J (12 floats each)
    float pfa[12], pfb[12];

    auto w_load = [&](int z) {   // fill pfa/pfb for slice z (zeros if OOB)
        const bool zok = (z >= 0) && (z < DD) && hok;
        const int rowb = z * S4 + gh * W4;
        #pragma unroll
        for (int k = 0; k < 3; ++k) {
            const int f = gf0 + k;
            float4 a = make_float4(0.f, 0.f, 0.f, 0.f);
            float4 b = make_float4(0.f, 0.f, 0.f, 0.f);
            if (zok && f >= 0 && f < W4) { a = Iv[rowb + f]; b = Jv[rowb + f]; }
            pfa[4*k] = a.x; pfa[4*k+1] = a.y; pfa[4*k+2] = a.z; pfa[4*k+3] = a.w;
            pfb[4*k] = b.x; pfb[4*k+1] = b.y; pfb[4*k+2] = b.z; pfb[4*k+3] = b.w;
        }
    };

    auto w_compute = [&]() {   // slide 9-tap W-sums from pfa/pfb -> SW
        float* wp = SW + wr * SW_RS + 4 * wc;
        #pragma unroll
        for (int ch = 0; ch < 5; ++ch) {
            float v[12];
            #pragma unroll
            for (int k = 0; k < 12; ++k)
                v[k] = (ch == 0) ? pfa[k]
                     : (ch == 1) ? pfb[k]
                     : (ch == 2) ? pfa[k] * pfa[k]
                     : (ch == 3) ? pfb[k] * pfb[k]
                     :             pfa[k] * pfb[k];
            float s = v[0];
            #pragma unroll
            for (int k = 1; k < 9; ++k) s += v[k];
            float4 o;
            o.x = s;
            s += v[9]  - v[0]; o.y = s;
            s += v[10] - v[1]; o.z = s;
            s += v[11] - v[2]; o.w = s;
            *(float4*)(wp + ch * SW_CS) = o;   // b128, 16B-aligned
        }
    };

    float q0[9], q1[9], q2[9], q3[9], q4[9];
    #pragma unroll
    for (int k = 0; k < 9; ++k) { q0[k]=0.f; q1[k]=0.f; q2[k]=0.f; q3[k]=0.f; q4[k]=0.f; }
    float r0=0.f, r1=0.f, r2=0.f, r3=0.f, r4=0.f;
    float acc = 0.f;

    // prologue: W(0) (slice dlo-4) -> SW; then prefetch slice dlo-3
    if (tid >= 128) {
        w_load(dlo - 4);
        if (dlo >= 4) w_compute();          // z0 < DD always (dlo <= 152)
        w_load(dlo - 3);
    }
    bar_lds_only();

    #pragma unroll 1
    for (int g = 0; g < 3; ++g) {
        #pragma unroll
        for (int ph = 0; ph < 9; ++ph) {
            const int i = 9 * g + ph;
            const int z = dlo - 4 + i;
            const bool val = (z >= 0) && (z < DD);   // block-uniform
            float* shW = (i & 1) ? SH1 : SH0;

            // ---- phase A: H(i): SW -> SH[i&1] ----
            if (tid < 160 && val) {
                const float* p = SW + hch * SW_CS + hcol;
                float v[16];
                #pragma unroll
                for (int r = 0; r < 16; r += 2) {   // pairs -> ds_read2_b32
                    const float* pr = p + r * SW_RS;
                    v[r]     = pr[0];
                    v[r + 1] = pr[SW_RS];
                }
                float s = v[0];
                #pragma unroll
                for (int r = 1; r < 9; ++r) s += v[r];
                float* o = shW + hcol * 5 + hch;    // [row][col][ch]
                float prev = s;
                o[0] = s;
                #pragma unroll
                for (int r = 1; r < TH; ++r) {
                    prev += v[r + 8] - v[r - 1];
                    o[r * (TW * 5)] = prev;
                }
            }
            bar_lds_only();   // barA: SH(i) visible to F; H done reading SW

            // ---- phase B: F(i) || W(i+1) ----
            float w0=0.f, w1=0.f, w2=0.f, w3=0.f, w4=0.f;
            if (val) {                               // issue F reads first
                const float* pF = shW + (ty * TW + tx) * 5;
                w0 = pF[0]; w1 = pF[1]; w2 = pF[2]; w3 = pF[3]; w4 = pF[4];
            }
            if (tid >= 128 && i < ITERS - 1) {
                const int zn = z + 1;
                if (zn >= 0 && zn < DD) w_compute();  // consume prefetch -> SW
                w_load(z + 2);                        // refill pf for i+1
            }
            r0 += w0 - q0[ph]; q0[ph] = w0;
            r1 += w1 - q1[ph]; q1[ph] = w1;
            r2 += w2 - q2[ph]; q2[ph] = w2;
            r3 += w3 - q3[ph]; q3[ph] = w3;
            r4 += w4 - q4[ph]; q4[ph] = w4;

            if (i >= 8 && (dlo + i - 8) < DD) {   // last chunk overhangs to 170
                float cross = r4 - r0 * r1 * INV_WSUM;
                float iv    = r2 - r0 * r0 * INV_WSUM;
                float jv    = r3 - r1 * r1 * INV_WSUM;
                acc += cross * cross * __builtin_amdgcn_rcpf(iv * jv + EPS);
            }
            bar_lds_only();   // barB: SW(i+1) visible to H(i+1); F done with SH
        }
    }

    // ---- block reduction -> one atomic (cold path: full __syncthreads ok) ----
    #pragma unroll
    for (int off = 32; off > 0; off >>= 1) acc += __shfl_down(acc, off, 64);
    if ((tid & 63) == 0) wred[tid >> 6] = acc;
    __syncthreads();
    if (tid == 0) {
        float t = 0.f;
        #pragma unroll
        for (int k = 0; k < NTHR / 64; ++k) t += wred[k];
        atomicAdd(out, t * (-1.0f / (float)NVOX));
    }
}

extern "C" void kernel_launch(void* const* d_in, const int* in_sizes, int n_in,
                              void* d_out, int out_size, void* d_ws, size_t ws_size,
                              hipStream_t stream) {
    const float* I = (const float*)d_in[0];
    const float* J = (const float*)d_in[1];
    float* out = (float*)d_out;

    hipMemsetAsync(d_out, 0, sizeof(float), stream);  // harness re-poisons d_out

    dim3 blk(NTHR, 1, 1);
    dim3 grd(WW / TW, HH / TH, (DD + DCH - 1) / DCH); // 7 x 24 x 9 = 1512 blocks
    ncc_fused<<<grd, blk, 0, stream>>>(I, J, out);
}

// Round 3
// 126.049 us; speedup vs baseline: 1.1350x; 1.1350x over previous
//
#include <hip/hip_runtime.h>

// NCC loss, win=9, (1,1,160,192,224) fp32 -> scalar. Fully fused, round 12.
// Model from R9-R11: time ~ total slice-iterations at fixed ~35% VALUBusy;
// co-residency capped ~4 blocks/CU; extra blocks don't help (R11 regression).
// The 65% idle is barrier-exposed latency: 2 barriers/slice, each making all
// waves wait on the straggler + an LDS round-trip.
// R12 = R10 config (DCH=28, 1008 blocks) with ONE structural change: SW is
// now DOUBLE-buffered, which lets all three roles run in a single phase with
// ONE barrier per slice (72 -> 37 barriers/block):
//   bar; { F(j): SH[j&1] -> ring/cc
//        || H(j+1): SW[(j+1)&1] -> SH[(j+1)&1]
//        || W(j+2): pf regs -> SW[(j+2)&1]; issue loads for j+3 }
// Parities alternate so no in-phase buffer overlap; every producer->consumer
// pair is separated by exactly one barrier (checked pairwise).
// Barriers stay LDS-only (vmcnt unconstrained) so pf global loads span them.
// LDS 33.3 KB -> still 4 blocks/CU (the measured cap).

#define DD 160
#define HH 192
#define WW 224
#define W4 56                 // WW/4
#define SLICE (HH * WW)
#define S4 (SLICE / 4)
#define NVOX (DD * SLICE)
#define TW 32
#define TH 8
#define DCH 28                // grid.z = 6 -> 1008 blocks (R10 best)
#define ITERS (DCH + 8)       // 36 = 4 * 9 (phase-static ring)
#define NTHR 256
#define SW_RS 36              // b128-aligned rows; 0-conflict pattern (R5/R7)
#define SW_CS (16 * SW_RS)    // 576 floats: 16 rows = TH + 8
#define SH_SZ (TH * TW * 5)   // 1280 floats
#define EPS 1e-5f
#define INV_WSUM (1.0f / 729.0f)

// Barrier that orders LDS only: s_waitcnt imm 0xC07F = lgkmcnt(0), vmcnt(63),
// expcnt(7) -> in-flight GLOBAL loads stay in flight across the barrier.
__device__ __forceinline__ void bar_lds_only() {
    __asm__ volatile("" ::: "memory");
    __builtin_amdgcn_s_waitcnt(0xC07F);
    __builtin_amdgcn_s_barrier();
    __asm__ volatile("" ::: "memory");
}

__global__ __launch_bounds__(NTHR, 4) void ncc_fused(const float* __restrict__ I,
                                                     const float* __restrict__ J,
                                                     float* __restrict__ out) {
    __shared__ float SW0[5 * SW_CS], SW1[5 * SW_CS];   // 11.52 KB each
    __shared__ float SH0[SH_SZ], SH1[SH_SZ];           // 5.12 KB each
    __shared__ float wred[NTHR / 64];

    const int tid = threadIdx.x;
    const int tx = tid & 31, ty = tid >> 5;    // F mapping: 32 x 8
    const int wlo = blockIdx.x * TW;
    const int hlo = blockIdx.y * TH;
    const int dlo = blockIdx.z * DCH;

    // W-group (tid >= 128): 16 rows x 8 f4-col groups
    const int wid = tid - 128;
    const int wr = wid >> 3, wc = wid & 7;
    const int gh = hlo - 4 + wr;
    const bool hok = (gh >= 0) && (gh < HH);
    const int gf0 = (wlo >> 2) - 1 + wc;

    // H-group (tid < 160): 5 channels x 32 cols, 8 out-rows each (16 reads)
    const int hcol = tid & 31, hch = tid >> 5;

    const float4* Iv = (const float4*)I;
    const float4* Jv = (const float4*)J;

    // prefetch registers: one slice-row of raw I/J (12 floats each)
    float pfa[12], pfb[12];

    auto w_load = [&](int z) {   // fill pfa/pfb for slice z (zeros if OOB)
        const bool zok = (z >= 0) && (z < DD) && hok;
        const int rowb = z * S4 + gh * W4;
        #pragma unroll
        for (int k = 0; k < 3; ++k) {
            const int f = gf0 + k;
            float4 a = make_float4(0.f, 0.f, 0.f, 0.f);
            float4 b = make_float4(0.f, 0.f, 0.f, 0.f);
            if (zok && f >= 0 && f < W4) { a = Iv[rowb + f]; b = Jv[rowb + f]; }
            pfa[4*k] = a.x; pfa[4*k+1] = a.y; pfa[4*k+2] = a.z; pfa[4*k+3] = a.w;
            pfb[4*k] = b.x; pfb[4*k+1] = b.y; pfb[4*k+2] = b.z; pfb[4*k+3] = b.w;
        }
    };

    auto w_compute = [&](float* dst) {   // slide 9-tap W-sums from pfa/pfb -> dst
        float* wp = dst + wr * SW_RS + 4 * wc;
        #pragma unroll
        for (int ch = 0; ch < 5; ++ch) {
            float v[12];
            #pragma unroll
            for (int k = 0; k < 12; ++k)
                v[k] = (ch == 0) ? pfa[k]
                     : (ch == 1) ? pfb[k]
                     : (ch == 2) ? pfa[k] * pfa[k]
                     : (ch == 3) ? pfb[k] * pfb[k]
                     :             pfa[k] * pfb[k];
            float s = v[0];
            #pragma unroll
            for (int k = 1; k < 9; ++k) s += v[k];
            float4 o;
            o.x = s;
            s += v[9]  - v[0]; o.y = s;
            s += v[10] - v[1]; o.z = s;
            s += v[11] - v[2]; o.w = s;
            *(float4*)(wp + ch * SW_CS) = o;   // b128, 16B-aligned
        }
    };

    auto h_phase = [&](const float* swSrc, float* shDst) {  // 9-tap H slide
        const float* p = swSrc + hch * SW_CS + hcol;
        float v[16];
        #pragma unroll
        for (int r = 0; r < 16; r += 2) {       // pairs -> ds_read2_b32
            const float* pr = p + r * SW_RS;
            v[r]     = pr[0];
            v[r + 1] = pr[SW_RS];
        }
        float s = v[0];
        #pragma unroll
        for (int r = 1; r < 9; ++r) s += v[r];
        float* o = shDst + hcol * 5 + hch;      // [row][col][ch]
        float prev = s;
        o[0] = s;
        #pragma unroll
        for (int r = 1; r < TH; ++r) {
            prev += v[r + 8] - v[r - 1];
            o[r * (TW * 5)] = prev;
        }
    };

    float q0[9], q1[9], q2[9], q3[9], q4[9];
    #pragma unroll
    for (int k = 0; k < 9; ++k) { q0[k]=0.f; q1[k]=0.f; q2[k]=0.f; q3[k]=0.f; q4[k]=0.f; }
    float r0=0.f, r1=0.f, r2=0.f, r3=0.f, r4=0.f;
    float acc = 0.f;

    // ---- prologue: W(0) -> SW0, prefetch slice 1 ----
    const int z0 = dlo - 4;
    if (tid >= 128) {
        w_load(z0);
        if (z0 >= 0) w_compute(SW0);        // z0 < DD always (dlo <= 140)
        w_load(z0 + 1);
    }
    bar_lds_only();

    // ---- P0: H(0), W(1), prefetch slice 2 (no F yet) ----
    if (tid < 160 && z0 >= 0) h_phase(SW0, SH0);
    if (tid >= 128) {
        const int z1 = z0 + 1;
        if (z1 >= 0 && z1 < DD) w_compute(SW1);
        w_load(z0 + 2);
    }

    // ---- main: 36 phases, ONE barrier each ----
    #pragma unroll 1
    for (int g = 0; g < 4; ++g) {
        #pragma unroll
        for (int ph = 0; ph < 9; ++ph) {
            const int j = 9 * g + ph;
            const int z = dlo - 4 + j;               // slice consumed by F(j)
            bar_lds_only();   // orders: H(j)->F(j), W(j+1)->H(j+1), F/H done w/ bufs

            // F(j): issue LDS reads first
            const bool val = (z >= 0) && (z < DD);   // block-uniform
            float* shR = (j & 1) ? SH1 : SH0;
            float w0=0.f, w1=0.f, w2=0.f, w3=0.f, w4=0.f;
            if (val) {
                const float* pF = shR + (ty * TW + tx) * 5;
                w0 = pF[0]; w1 = pF[1]; w2 = pF[2]; w3 = pF[3]; w4 = pF[4];
            }

            // H(j+1): SW[(j+1)&1] -> SH[(j+1)&1]   (guard j+1 <= ITERS-1)
            if ((g < 3 || ph < 8) && tid < 160) {
                const int zh = z + 1;
                if (zh >= 0 && zh < DD)
                    h_phase((j & 1) ? SW0 : SW1, (j & 1) ? SH0 : SH1);
            }

            // W(j+2): pf regs -> SW[(j+2)&1]; refill pf   (guard j+2 <= ITERS-1)
            if ((g < 3 || ph < 7) && tid >= 128) {
                const int zw = z + 2;
                if (zw >= 0 && zw < DD) w_compute((j & 1) ? SW1 : SW0);
                w_load(z + 3);
            }

            // ring update + cc
            r0 += w0 - q0[ph]; q0[ph] = w0;
            r1 += w1 - q1[ph]; q1[ph] = w1;
            r2 += w2 - q2[ph]; q2[ph] = w2;
            r3 += w3 - q3[ph]; q3[ph] = w3;
            r4 += w4 - q4[ph]; q4[ph] = w4;

            if (j >= 8 && (dlo + j - 8) < DD) {   // last chunk overhangs to 167
                float cross = r4 - r0 * r1 * INV_WSUM;
                float iv    = r2 - r0 * r0 * INV_WSUM;
                float jv    = r3 - r1 * r1 * INV_WSUM;
                acc += cross * cross * __builtin_amdgcn_rcpf(iv * jv + EPS);
            }
        }
    }

    // ---- block reduction -> one atomic (cold path: full __syncthreads ok) ----
    #pragma unroll
    for (int off = 32; off > 0; off >>= 1) acc += __shfl_down(acc, off, 64);
    if ((tid & 63) == 0) wred[tid >> 6] = acc;
    __syncthreads();
    if (tid == 0) {
        float t = 0.f;
        #pragma unroll
        for (int k = 0; k < NTHR / 64; ++k) t += wred[k];
        atomicAdd(out, t * (-1.0f / (float)NVOX));
    }
}

extern "C" void kernel_launch(void* const* d_in, const int* in_sizes, int n_in,
                              void* d_out, int out_size, void* d_ws, size_t ws_size,
                              hipStream_t stream) {
    const float* I = (const float*)d_in[0];
    const float* J = (const float*)d_in[1];
    float* out = (float*)d_out;

    hipMemsetAsync(d_out, 0, sizeof(float), stream);  // harness re-poisons d_out

    dim3 blk(NTHR, 1, 1);
    dim3 grd(WW / TW, HH / TH, (DD + DCH - 1) / DCH); // 7 x 24 x 6 = 1008 blocks
    ncc_fused<<<grd, blk, 0, stream>>>(I, J, out);
}